// Round 12
// baseline (66.950 us; speedup 1.0000x reference)
//
#include <hip/hip_runtime.h>
#include <hip/hip_bf16.h>
#include <stdint.h>

#define NB 4
#define NT 2048
#define NC 1024
#define NH 128
#define ND 8
#define NTOK (NB*NT)      // 8192 tokens
#define GK 1024           // GEMM K
#define GN 1024           // GEMM N

typedef __attribute__((ext_vector_type(4))) float f32x4;
typedef __attribute__((ext_vector_type(8))) short bf16x8;
typedef __attribute__((ext_vector_type(8))) _Float16 f16x8;
typedef __attribute__((ext_vector_type(2))) _Float16 f16x2;
typedef __attribute__((ext_vector_type(4))) unsigned int u32x4;
typedef __attribute__((ext_vector_type(2))) unsigned int u32x2;
typedef unsigned int uint32;

// GAMMA = sqrt(log2(e)/sqrt(8)) folded into q' so exp2(S) needs no scale.
// C1INV = 1/GAMMA corrects the PV output (V = gamma*q); ones-cols are 1.0h.
#define GAMMA  0.71419167f
#define C1INV  1.4001844f

#define GLOAD_LDS16(g, l) \
  __builtin_amdgcn_global_load_lds((const __attribute__((address_space(1))) void*)(g), \
                                   (__attribute__((address_space(3))) void*)(l), 16, 0, 0)

__device__ __forceinline__ unsigned short f2bf(float f) {
  __bf16 b = (__bf16)f;
  return __builtin_bit_cast(unsigned short, b);
}
__device__ __forceinline__ f16x2 cvtpk_f16(float a, float b) {
  return __builtin_bit_cast(f16x2, __builtin_amdgcn_cvt_pkrtz(a, b));
}

// packed-f16 exp2: |s|<=4.08; magic-add RNE round, deg-3 Taylor x 2^-8,
// exponent injection (carry-safe, masked). Verified R8 (absmax 0.0078).
__device__ __forceinline__ uint32 exp2pk(float a, float b) {
  f16x2 s = cvtpk_f16(a, b);
  const f16x2 MAGIC = {(_Float16)1536.0f, (_Float16)1536.0f};
  f16x2 t = s + MAGIC;
  f16x2 f = s - (t - MAGIC);
  const _Float16 k3 = (_Float16)(0.0555041f / 256.0f);
  const _Float16 k2 = (_Float16)(0.2402265f / 256.0f);
  const _Float16 k1 = (_Float16)(0.6931472f / 256.0f);
  const _Float16 k0 = (_Float16)(1.0f / 256.0f);
  const f16x2 P3 = {k3, k3}, P2 = {k2, k2}, P1 = {k1, k1}, P0 = {k0, k0};
  f16x2 p = P2 + f * P3;
  p = P1 + f * p;
  p = P0 + f * p;
  uint32 tb = __builtin_bit_cast(uint32, t);
  uint32 inj = ((((tb << 10) & 0xFC00FC00u) + 0x20002000u) & 0xFC00FC00u);
  return __builtin_bit_cast(uint32, p) + inj;
}

// ---------------- W fp32 -> bf16 ----------------
__global__ __launch_bounds__(256) void wconv_kernel(const float4* __restrict__ w,
                                                    ushort4* __restrict__ wb) {
  int i = blockIdx.x * 256 + threadIdx.x;
  float4 v = w[i];
  ushort4 o;
  o.x = f2bf(v.x); o.y = f2bf(v.y); o.z = f2bf(v.z); o.w = f2bf(v.w);
  wb[i] = o;
}

// ---- per-token attention: batched-phase, 2 tokens/wave, persistent blocks ---
// R11 post-mortem: 5 structures all ~43us; chain-bound (17 cyc/issue/wave).
// This version: (1) per b-block, ALL 8 S-MFMAs then ALL 16 exp2pk then 4 PV
// (overlapped latencies instead of 4 serial units); (2) 1024 blocks x 4 waves,
// 2 tokens/wave with both tokens' x loaded up-front (sustained residency,
// cross-token overlap); launch_bounds(256,3) raises the VGPR cap to ~170.
// Fragment maps (HW-verified): A/B: lane l -> row/col l&15, k-slot (l>>4)*8+e;
// C/D: m=(l>>4)*4+r, n=l&15. sigma_S(8t+e)=2t+e; S symmetric => packed exp2
// pairs of S-blocks (2j,2j+1) ARE the PV A-fragment under sigma_j; PV B reads
// sigma_j-permuted QT rows; B cols 8..15 = 1.0h carry the rowsum.
#define QTS 136   // QT row stride (elements); 272B rows spread banks

__device__ __forceinline__ void process_token(const float2* __restrict__ xv,
                                              float S, unsigned short* qt,
                                              unsigned short* __restrict__ orow,
                                              int c, int t) {
  // prologue: q' = GAMMA*cos(x+S); lane holds rows 16a+c, dims 2t,2t+1
  u32x4 qf[8];
#pragma unroll
  for (int a = 0; a < 8; ++a) {
    float q0 = GAMMA * __cosf(xv[a].x + S);
    float q1 = GAMMA * __cosf(xv[a].y + S);
    uint32 pk = __builtin_bit_cast(uint32, cvtpk_f16(q0, q1));
    qt[(2 * t) * QTS + 16 * a + c] = (unsigned short)(pk & 0xFFFFu);
    qt[(2 * t + 1) * QTS + 16 * a + c] = (unsigned short)(pk >> 16);
    qf[a].x = pk;
    qf[a].y = 0u; qf[a].z = 0u; qf[a].w = 0u;
  }

  // PV B-fragments: element e of frag j = Vext[32j+4t+(e&3)+16(e>>2)][c];
  // cols c>=8 -> 1.0h ones (rowsum carrier).
  u32x4 bff[4];
  {
    const int cm = (c < 8) ? c : 7;
    const bool isq = (c < 8);
    const uint32 onepair = 0x3C003C00u;
#pragma unroll
    for (int j = 0; j < 4; ++j) {
      u32x2 v0 = *(const u32x2*)&qt[cm * QTS + 32 * j + 4 * t];
      u32x2 v1 = *(const u32x2*)&qt[cm * QTS + 32 * j + 16 + 4 * t];
      bff[j].x = isq ? v0.x : onepair;
      bff[j].y = isq ? v0.y : onepair;
      bff[j].z = isq ? v1.x : onepair;
      bff[j].w = isq ? v1.y : onepair;
    }
  }

  const f32x4 z4 = {0.f, 0.f, 0.f, 0.f};

#pragma unroll
  for (int b = 0; b < 8; ++b) {        // P-row block: rows 16b..16b+15
    // phase 1: ALL 8 S-MFMAs back-to-back (latencies overlap in the pipe)
    f32x4 sv[8];
#pragma unroll
    for (int j = 0; j < 4; ++j) {
      sv[2 * j] = __builtin_amdgcn_mfma_f32_16x16x32_f16(
          __builtin_bit_cast(f16x8, qf[2 * j]), __builtin_bit_cast(f16x8, qf[b]),
          z4, 0, 0, 0);
      sv[2 * j + 1] = __builtin_amdgcn_mfma_f32_16x16x32_f16(
          __builtin_bit_cast(f16x8, qf[2 * j + 1]), __builtin_bit_cast(f16x8, qf[b]),
          z4, 0, 0, 0);
    }
    // phase 2: ALL 16 exp2pk (16 independent dependency chains)
    u32x4 af[4];
#pragma unroll
    for (int j = 0; j < 4; ++j) {
      af[j].x = exp2pk(sv[2 * j][0], sv[2 * j][1]);
      af[j].y = exp2pk(sv[2 * j][2], sv[2 * j][3]);
      af[j].z = exp2pk(sv[2 * j + 1][0], sv[2 * j + 1][1]);
      af[j].w = exp2pk(sv[2 * j + 1][2], sv[2 * j + 1][3]);
    }
    // phase 3: 4 PV MFMAs (accumulator chain)
    f32x4 o = z4;
#pragma unroll
    for (int j = 0; j < 4; ++j)
      o = __builtin_amdgcn_mfma_f32_16x16x32_f16(
          __builtin_bit_cast(f16x8, af[j]), __builtin_bit_cast(f16x8, bff[j]),
          o, 0, 0, 0);
    // epilogue: rowsum at col c+8 (lane l^8, same reg)
#pragma unroll
    for (int r = 0; r < 4; ++r) {
      float rs = __shfl_xor(o[r], 8, 64);
      float outv = o[r] * __builtin_amdgcn_rcpf(rs) * C1INV;
      if (c < 8)
        orow[(16 * b + 4 * t + r) * ND + c] = f2bf(outv);
    }
  }
}

__global__ __launch_bounds__(256, 3) void attn_kernel(const float* __restrict__ x,
                                                      const float* __restrict__ theta,
                                                      unsigned short* __restrict__ aout) {
  __shared__ __align__(16) unsigned short QT[4][8 * QTS];   // 8704 B / block

  const int tid = (int)threadIdx.x;
  const int wid = tid >> 6;                 // 0..3
  const int tok0 = blockIdx.x * 4 + wid;    // first token
  const int tok1 = tok0 + 4096;             // second token (grid-stride)
  const int l = tid & 63;
  const int c = l & 15;
  const int t = l >> 4;

  float S = 0.f;
#pragma unroll
  for (int j = 0; j < ND; ++j) S += theta[j];

  // issue BOTH tokens' x loads up-front: token1's HBM latency hides under
  // token0's entire compute (T14 issue-early).
  float2 xv0[8], xv1[8];
#pragma unroll
  for (int a = 0; a < 8; ++a)
    xv0[a] = *(const float2*)(x + (size_t)tok0 * NC + (16 * a + c) * ND + 2 * t);
#pragma unroll
  for (int a = 0; a < 8; ++a)
    xv1[a] = *(const float2*)(x + (size_t)tok1 * NC + (16 * a + c) * ND + 2 * t);

  unsigned short* qt = &QT[wid][0];
  process_token(xv0, S, qt, aout + (size_t)tok0 * NC, c, t);
  process_token(xv1, S, qt, aout + (size_t)tok1 * NC, c, t);
}

// ---------------- projection GEMM: y[M,N] = A[M,K] * Bt[N,K]^T ----------------
// 128x128 tile, BK=64, 8 waves (2x4), double-buffered LDS, counted vmcnt +
// raw s_barrier prefetch pipeline, chunk-XOR swizzle.  [R6: passed]
#define BM 128
#define BN 128
#define BK 64

__global__ __launch_bounds__(512, 4) void gemm_kernel(const unsigned short* __restrict__ A,
                                                      const unsigned short* __restrict__ Bt,
                                                      float* __restrict__ C) {
  __shared__ __align__(16) unsigned short As[2][BM * BK];  // 2 x 16 KB
  __shared__ __align__(16) unsigned short Bs[2][BN * BK];  // 2 x 16 KB

  const int bm = blockIdx.x;
  const int bn = blockIdx.y;
  const int tid = (int)threadIdx.x;
  const int l = tid & 63;
  const int w = tid >> 6;        // wave 0..7
  const int wm = w >> 2;         // 0..1 over M (64-row halves)
  const int wn = w & 3;          // 0..3 over N (32-col quarters)

  f32x4 acc[4][2] = {};

  const int srow = l >> 3;                   // 0..7 within 8-row group
  const int schk = (l & 7) ^ srow;           // inverse-swizzled source chunk
  const unsigned short* gA0 = A + (size_t)(bm * BM + 16 * w + srow) * GK + schk * 8;
  const unsigned short* gA1 = gA0 + 8 * GK;
  const unsigned short* gB0 = Bt + (size_t)(bn * BN + 16 * w + srow) * GK + schk * 8;
  const unsigned short* gB1 = gB0 + 8 * GK;

  const int fr = l & 15;                     // fragment row
  const int kcb = l >> 4;                    // k-chunk base (0..3)
  const int fx = l & 7;                      // row-XOR for swizzled read

#define STAGE(nb)                                          \
  {                                                        \
    unsigned short* la = &As[nb][(16 * w) * BK];           \
    unsigned short* lb = &Bs[nb][(16 * w) * BK];           \
    GLOAD_LDS16(gA0, la);                                  \
    GLOAD_LDS16(gA1, la + 8 * BK);                         \
    GLOAD_LDS16(gB0, lb);                                  \
    GLOAD_LDS16(gB1, lb + 8 * BK);                         \
    gA0 += BK; gA1 += BK; gB0 += BK; gB1 += BK;            \
  }

  auto compute = [&](const unsigned short* as, const unsigned short* bs) {
#pragma unroll
    for (int s = 0; s < 2; ++s) {            // k-halves of BK=64
      const int slot = ((4 * s + kcb) ^ fx) * 8;
      bf16x8 af[4], bfr[2];
#pragma unroll
      for (int i = 0; i < 4; ++i)
        af[i] = *reinterpret_cast<const bf16x8*>(&as[(64 * wm + 16 * i + fr) * BK + slot]);
#pragma unroll
      for (int j = 0; j < 2; ++j)
        bfr[j] = *reinterpret_cast<const bf16x8*>(&bs[(32 * wn + 16 * j + fr) * BK + slot]);

#pragma unroll
      for (int i = 0; i < 4; ++i)
#pragma unroll
        for (int j = 0; j < 2; ++j)
          acc[i][j] = __builtin_amdgcn_mfma_f32_16x16x32_bf16(af[i], bfr[j], acc[i][j], 0, 0, 0);
    }
  };

  STAGE(0);

  int buf = 0;
#pragma unroll 1
  for (int t = 0; t < 15; ++t) {
    STAGE(buf ^ 1);                          // issue next tile first
    asm volatile("s_waitcnt vmcnt(4)" ::: "memory");   // current tile landed
    __builtin_amdgcn_s_barrier();
    asm volatile("" ::: "memory");
    compute(&As[buf][0], &Bs[buf][0]);
    asm volatile("" ::: "memory");
    __builtin_amdgcn_s_barrier();            // reads done before next overwrite
    asm volatile("" ::: "memory");
    buf ^= 1;
  }
  asm volatile("s_waitcnt vmcnt(0)" ::: "memory");
  __builtin_amdgcn_s_barrier();
  asm volatile("" ::: "memory");
  compute(&As[1][0], &Bs[1][0]);

  float* Cb = C + (size_t)(bm * BM + 64 * wm) * GN + bn * BN + 32 * wn;
  const int cr = (l >> 4) * 4;
  const int cc = l & 15;
#pragma unroll
  for (int i = 0; i < 4; ++i)
#pragma unroll
    for (int j = 0; j < 2; ++j)
#pragma unroll
      for (int r = 0; r < 4; ++r)
        Cb[(size_t)(16 * i + cr + r) * GN + 16 * j + cc] = acc[i][j][r];
#undef STAGE
}

extern "C" void kernel_launch(void* const* d_in, const int* in_sizes, int n_in,
                              void* d_out, int out_size, void* d_ws, size_t ws_size,
                              hipStream_t stream) {
  (void)in_sizes; (void)n_in; (void)out_size; (void)ws_size;
  const float* x = (const float*)d_in[0];
  const float* theta = (const float*)d_in[1];
  const float* wproj = (const float*)d_in[2];
  float* y = (float*)d_out;

  unsigned short* attn_out = (unsigned short*)d_ws;                            // 16 MB bf16
  unsigned short* wb = (unsigned short*)((char*)d_ws + (size_t)NTOK * NC * 2); // 2 MB bf16

  wconv_kernel<<<(NC * NC / 4) / 256, 256, 0, stream>>>((const float4*)wproj,
                                                        (ushort4*)wb);
  attn_kernel<<<NTOK / 8, 256, 0, stream>>>(x, theta, attn_out);
  dim3 grid(NTOK / BM, GN / BN);
  gemm_kernel<<<grid, 512, 0, stream>>>(attn_out, wb, y);
}

// Round 13
// 64.979 us; speedup vs baseline: 1.0303x; 1.0303x over previous
//
#include <hip/hip_runtime.h>
#include <hip/hip_bf16.h>
#include <stdint.h>

#define NB 4
#define NT 2048
#define NC 1024
#define NH 128
#define ND 8
#define NTOK (NB*NT)      // 8192 tokens
#define GK 1024           // GEMM K
#define GN 1024           // GEMM N

typedef __attribute__((ext_vector_type(4))) float f32x4;
typedef __attribute__((ext_vector_type(8))) short bf16x8;
typedef __attribute__((ext_vector_type(8))) _Float16 f16x8;
typedef __attribute__((ext_vector_type(4))) _Float16 f16x4;
typedef __attribute__((ext_vector_type(2))) _Float16 f16x2;
typedef __attribute__((ext_vector_type(4))) unsigned int u32x4;
typedef __attribute__((ext_vector_type(2))) unsigned int u32x2;
typedef unsigned int uint32;

// GAMMA = sqrt(log2(e)/sqrt(8)) folded into q' so exp2(S) needs no scale.
// C1INV = 1/GAMMA corrects the PV output (V = gamma*q); ones-cols are 1.0h.
#define GAMMA  0.71419167f
#define C1INV  1.4001844f

#define GLOAD_LDS16(g, l) \
  __builtin_amdgcn_global_load_lds((const __attribute__((address_space(1))) void*)(g), \
                                   (__attribute__((address_space(3))) void*)(l), 16, 0, 0)

__device__ __forceinline__ unsigned short f2bf(float f) {
  __bf16 b = (__bf16)f;
  return __builtin_bit_cast(unsigned short, b);
}
__device__ __forceinline__ f16x2 cvtpk_f16(float a, float b) {
  return __builtin_bit_cast(f16x2, __builtin_amdgcn_cvt_pkrtz(a, b));
}

// packed-f16 exp2: |s|<=4.08; magic-add RNE round, deg-3 Taylor x 2^-8,
// exponent injection (carry-safe, masked). Verified R8 (absmax 0.0078).
__device__ __forceinline__ uint32 exp2pk(float a, float b) {
  f16x2 s = cvtpk_f16(a, b);
  const f16x2 MAGIC = {(_Float16)1536.0f, (_Float16)1536.0f};
  f16x2 t = s + MAGIC;
  f16x2 f = s - (t - MAGIC);
  const _Float16 k3 = (_Float16)(0.0555041f / 256.0f);
  const _Float16 k2 = (_Float16)(0.2402265f / 256.0f);
  const _Float16 k1 = (_Float16)(0.6931472f / 256.0f);
  const _Float16 k0 = (_Float16)(1.0f / 256.0f);
  const f16x2 P3 = {k3, k3}, P2 = {k2, k2}, P1 = {k1, k1}, P0 = {k0, k0};
  f16x2 p = P2 + f * P3;
  p = P1 + f * p;
  p = P0 + f * p;
  uint32 tb = __builtin_bit_cast(uint32, t);
  uint32 inj = ((((tb << 10) & 0xFC00FC00u) + 0x20002000u) & 0xFC00FC00u);
  return __builtin_bit_cast(uint32, p) + inj;
}

// ---------------- W fp32 -> bf16 ----------------
__global__ __launch_bounds__(256) void wconv_kernel(const float4* __restrict__ w,
                                                    ushort4* __restrict__ wb) {
  int i = blockIdx.x * 256 + threadIdx.x;
  float4 v = w[i];
  ushort4 o;
  o.x = f2bf(v.x); o.y = f2bf(v.y); o.z = f2bf(v.z); o.w = f2bf(v.w);
  wb[i] = o;
}

// ---- per-token attention: K=16 MFMA, minimal register footprint ------------
// R12 post-mortem: all MFMA variants stick at occ 26-40% (vs 63% for the
// MFMA-free R1) -> suspected unified-VGPR/AGPR budget, never varied. This
// version: mfma_f32_16x16x16f16 (2-reg operands: qf = {pk,0} halves operand
// regs; no zero-triples), and the K=16 C/D map (m=4t+r) makes S-block(m,b)
// reg r = P[16b+c][16m+4t+r] = exactly PV chunk m's k-slots -> af feeds PV
// directly, sv/af live range is one m-iter. launch_bounds(128,6).
// K=16 maps (canonical family of the HW-verified 16x16x32 maps):
//   A/B: lane l -> row/col l&15, k-slot (l>>4)*4+e (e=0..3)
//   C/D: lane l reg r -> m=(l>>4)*4+r, n=l&15
// sigma_S(4t+e) = dim 2t+e (e<2, else zero-slot): both S operands are the
// lane's OWN cos values; full 8-dim dot via the 8 populated slots.
#define QTS 136   // QT row stride (elements); 272B rows spread banks

__global__ __launch_bounds__(128, 6) void attn_kernel(const float* __restrict__ x,
                                                      const float* __restrict__ theta,
                                                      unsigned short* __restrict__ aout) {
  __shared__ __align__(16) unsigned short QT[2][8 * QTS];   // 4352 B / block

  const int tid = (int)threadIdx.x;
  const int wid = tid >> 6;                 // 0..1
  const int tok = blockIdx.x * 2 + wid;
  const int l = tid & 63;
  const int c = l & 15;
  const int t = l >> 4;

  float S = 0.f;
#pragma unroll
  for (int j = 0; j < ND; ++j) S += theta[j];

  // q' = GAMMA*cos(x+S); lane holds rows 16a+c, dims 2t,2t+1 -> f16 pair.
  // qf[a] = {pk, 0}: slots 4t,4t+1 = dims 2t,2t+1; slots 4t+2,4t+3 = 0.
  u32x2 qf[8];
  unsigned short* qt = &QT[wid][0];
#pragma unroll
  for (int a = 0; a < 8; ++a) {
    float2 xv = *(const float2*)(x + (size_t)tok * NC + (16 * a + c) * ND + 2 * t);
    float q0 = GAMMA * __cosf(xv.x + S);
    float q1 = GAMMA * __cosf(xv.y + S);
    uint32 pk = __builtin_bit_cast(uint32, cvtpk_f16(q0, q1));
    qt[(2 * t) * QTS + 16 * a + c] = (unsigned short)(pk & 0xFFFFu);
    qt[(2 * t + 1) * QTS + 16 * a + c] = (unsigned short)(pk >> 16);
    qf[a].x = pk;
    qf[a].y = 0u;
  }

  // PV B-fragments, chunk m: element e = V[16m+4t+e][c] = QT[c][16m+4t+e]
  // (contiguous u32x2); cols c>=8 -> 1.0h ones (rowsum carrier).
  u32x2 bff[8];
  {
    const int cm = (c < 8) ? c : 7;
    const bool isq = (c < 8);
    const uint32 ONE2 = 0x3C003C00u;
#pragma unroll
    for (int m = 0; m < 8; ++m) {
      u32x2 v = *(const u32x2*)&qt[cm * QTS + 16 * m + 4 * t];
      bff[m].x = isq ? v.x : ONE2;
      bff[m].y = isq ? v.y : ONE2;
    }
  }

  const f32x4 z4 = {0.f, 0.f, 0.f, 0.f};
  unsigned short* orow = aout + (size_t)tok * NC;

#pragma unroll
  for (int b = 0; b < 8; ++b) {        // P-row block: rows 16b..16b+15
    f32x4 o = z4;
#pragma unroll
    for (int m = 0; m < 8; ++m) {      // g-chunk 16m..16m+15
      // S-block(m,b): lane(c,t) reg r = S[16m+4t+r][16b+c] = P[16b+c][16m+4t+r]
      f32x4 sv = __builtin_amdgcn_mfma_f32_16x16x16f16(
          __builtin_bit_cast(f16x4, qf[m]), __builtin_bit_cast(f16x4, qf[b]),
          z4, 0, 0, 0);
      // p = 2^S: regs r=0..3 ARE PV chunk m's k-slots 4t+0..3 -> direct A-frag
      u32x2 afw;
      afw.x = exp2pk(sv[0], sv[1]);
      afw.y = exp2pk(sv[2], sv[3]);
      o = __builtin_amdgcn_mfma_f32_16x16x16f16(
          __builtin_bit_cast(f16x4, afw), __builtin_bit_cast(f16x4, bff[m]),
          o, 0, 0, 0);
    }
    // o reg r = O'[16b+4t+r][c]; rowsum at col c+8 (lane l^8, same reg)
#pragma unroll
    for (int r = 0; r < 4; ++r) {
      float rs = __shfl_xor(o[r], 8, 64);
      float outv = o[r] * __builtin_amdgcn_rcpf(rs) * C1INV;
      if (c < 8)
        orow[(16 * b + 4 * t + r) * ND + c] = f2bf(outv);
    }
  }
}

// ---------------- projection GEMM: y[M,N] = A[M,K] * Bt[N,K]^T ----------------
// 128x128 tile, BK=64, 8 waves (2x4), double-buffered LDS, counted vmcnt +
// raw s_barrier prefetch pipeline, chunk-XOR swizzle.  [R6: passed]
#define BM 128
#define BN 128
#define BK 64

__global__ __launch_bounds__(512, 4) void gemm_kernel(const unsigned short* __restrict__ A,
                                                      const unsigned short* __restrict__ Bt,
                                                      float* __restrict__ C) {
  __shared__ __align__(16) unsigned short As[2][BM * BK];  // 2 x 16 KB
  __shared__ __align__(16) unsigned short Bs[2][BN * BK];  // 2 x 16 KB

  const int bm = blockIdx.x;
  const int bn = blockIdx.y;
  const int tid = (int)threadIdx.x;
  const int l = tid & 63;
  const int w = tid >> 6;        // wave 0..7
  const int wm = w >> 2;         // 0..1 over M (64-row halves)
  const int wn = w & 3;          // 0..3 over N (32-col quarters)

  f32x4 acc[4][2] = {};

  const int srow = l >> 3;                   // 0..7 within 8-row group
  const int schk = (l & 7) ^ srow;           // inverse-swizzled source chunk
  const unsigned short* gA0 = A + (size_t)(bm * BM + 16 * w + srow) * GK + schk * 8;
  const unsigned short* gA1 = gA0 + 8 * GK;
  const unsigned short* gB0 = Bt + (size_t)(bn * BN + 16 * w + srow) * GK + schk * 8;
  const unsigned short* gB1 = gB0 + 8 * GK;

  const int fr = l & 15;                     // fragment row
  const int kcb = l >> 4;                    // k-chunk base (0..3)
  const int fx = l & 7;                      // row-XOR for swizzled read

#define STAGE(nb)                                          \
  {                                                        \
    unsigned short* la = &As[nb][(16 * w) * BK];           \
    unsigned short* lb = &Bs[nb][(16 * w) * BK];           \
    GLOAD_LDS16(gA0, la);                                  \
    GLOAD_LDS16(gA1, la + 8 * BK);                         \
    GLOAD_LDS16(gB0, lb);                                  \
    GLOAD_LDS16(gB1, lb + 8 * BK);                         \
    gA0 += BK; gA1 += BK; gB0 += BK; gB1 += BK;            \
  }

  auto compute = [&](const unsigned short* as, const unsigned short* bs) {
#pragma unroll
    for (int s = 0; s < 2; ++s) {            // k-halves of BK=64
      const int slot = ((4 * s + kcb) ^ fx) * 8;
      bf16x8 af[4], bfr[2];
#pragma unroll
      for (int i = 0; i < 4; ++i)
        af[i] = *reinterpret_cast<const bf16x8*>(&as[(64 * wm + 16 * i + fr) * BK + slot]);
#pragma unroll
      for (int j = 0; j < 2; ++j)
        bfr[j] = *reinterpret_cast<const bf16x8*>(&bs[(32 * wn + 16 * j + fr) * BK + slot]);

#pragma unroll
      for (int i = 0; i < 4; ++i)
#pragma unroll
        for (int j = 0; j < 2; ++j)
          acc[i][j] = __builtin_amdgcn_mfma_f32_16x16x32_bf16(af[i], bfr[j], acc[i][j], 0, 0, 0);
    }
  };

  STAGE(0);

  int buf = 0;
#pragma unroll 1
  for (int t = 0; t < 15; ++t) {
    STAGE(buf ^ 1);                          // issue next tile first
    asm volatile("s_waitcnt vmcnt(4)" ::: "memory");   // current tile landed
    __builtin_amdgcn_s_barrier();
    asm volatile("" ::: "memory");
    compute(&As[buf][0], &Bs[buf][0]);
    asm volatile("" ::: "memory");
    __builtin_amdgcn_s_barrier();            // reads done before next overwrite
    asm volatile("" ::: "memory");
    buf ^= 1;
  }
  asm volatile("s_waitcnt vmcnt(0)" ::: "memory");
  __builtin_amdgcn_s_barrier();
  asm volatile("" ::: "memory");
  compute(&As[1][0], &Bs[1][0]);

  float* Cb = C + (size_t)(bm * BM + 64 * wm) * GN + bn * BN + 32 * wn;
  const int cr = (l >> 4) * 4;
  const int cc = l & 15;
#pragma unroll
  for (int i = 0; i < 4; ++i)
#pragma unroll
    for (int j = 0; j < 2; ++j)
#pragma unroll
      for (int r = 0; r < 4; ++r)
        Cb[(size_t)(16 * i + cr + r) * GN + 16 * j + cc] = acc[i][j][r];
#undef STAGE
}

extern "C" void kernel_launch(void* const* d_in, const int* in_sizes, int n_in,
                              void* d_out, int out_size, void* d_ws, size_t ws_size,
                              hipStream_t stream) {
  (void)in_sizes; (void)n_in; (void)out_size; (void)ws_size;
  const float* x = (const float*)d_in[0];
  const float* theta = (const float*)d_in[1];
  const float* wproj = (const float*)d_in[2];
  float* y = (float*)d_out;

  unsigned short* attn_out = (unsigned short*)d_ws;                            // 16 MB bf16
  unsigned short* wb = (unsigned short*)((char*)d_ws + (size_t)NTOK * NC * 2); // 2 MB bf16

  wconv_kernel<<<(NC * NC / 4) / 256, 256, 0, stream>>>((const float4*)wproj,
                                                        (ushort4*)wb);
  attn_kernel<<<NTOK / 2, 128, 0, stream>>>(x, theta, attn_out);
  dim3 grid(NTOK / BM, GN / BN);
  gemm_kernel<<<grid, 512, 0, stream>>>(attn_out, wb, y);
}